// Round 1
// baseline (332.091 us; speedup 1.0000x reference)
//
#include <hip/hip_runtime.h>

typedef short bf16x8 __attribute__((ext_vector_type(8)));
typedef float f32x4 __attribute__((ext_vector_type(4)));
typedef unsigned short u16;
typedef unsigned short u16x4 __attribute__((ext_vector_type(4)));
typedef unsigned short u16x8 __attribute__((ext_vector_type(8)));

#define NB 4
#define LEN 1024
#define DM 1024
#define NH 16
#define HD 64

__device__ __forceinline__ u16 f2bf(float f) {
    union { float f; unsigned u; } v; v.f = f;
    return (u16)((v.u + 0x7fffu + ((v.u >> 16) & 1u)) >> 16);
}

__device__ __forceinline__ f32x4 mfma16(bf16x8 a, bf16x8 b, f32x4 c) {
    return __builtin_amdgcn_mfma_f32_16x16x32_bf16(a, b, c, 0, 0, 0);
}

// ---------------- cast fp32 -> bf16 (vectorized) ----------------
__global__ void cast_f32_bf16(const float* __restrict__ in, u16* __restrict__ out, int n4) {
    int i = blockIdx.x * blockDim.x + threadIdx.x;
    if (i < n4) {
        float4 v = ((const float4*)in)[i];
        u16x4 o;
        o[0] = f2bf(v.x); o[1] = f2bf(v.y); o[2] = f2bf(v.z); o[3] = f2bf(v.w);
        ((u16x4*)out)[i] = o;
    }
}

// ---------------- transpose + cast weights: W[K][N] -> WT[N][K] bf16 ----------------
__global__ void transpose_cast(const float* __restrict__ W, u16* __restrict__ WT, int K, int N) {
    __shared__ float tile[32][33];
    int n0 = blockIdx.x * 32, k0 = blockIdx.y * 32;
    int tx = threadIdx.x, ty = threadIdx.y;
    #pragma unroll
    for (int j = 0; j < 4; j++) {
        int r = ty + j * 8;
        tile[r][tx] = W[(size_t)(k0 + r) * N + n0 + tx];
    }
    __syncthreads();
    #pragma unroll
    for (int j = 0; j < 4; j++) {
        int r = ty + j * 8;  // local n
        WT[(size_t)(n0 + r) * K + k0 + tx] = f2bf(tile[tx][r]);
    }
}

// ---------------- r = pos_embed @ Wr  (2048x64 @ 64x64) -> bf16 ----------------
__global__ void r_proj(const float* __restrict__ pos, const float* __restrict__ Wr,
                       u16* __restrict__ rbf) {
    int idx = blockIdx.x * 256 + threadIdx.x;  // 2048*64 = 131072
    int row = idx >> 6, col = idx & 63;
    float s = 0.f;
    #pragma unroll
    for (int kk = 0; kk < 64; kk++) s += pos[row * 64 + kk] * Wr[kk * 64 + col];
    rbf[idx] = f2bf(s);
}

// ---------------- projection GEMM: C = A(bf16 MxK) @ WT^T, fused epilogues ----------------
// mode 0: out1 = (C + rrb)*0.125 -> A1[b,h,l,d]; out2 = (C + rwb)*0.125 -> A2
// mode 1: n<1024 -> out1 = C -> khs[b,h,l,d]; n>=1024 -> out2 = C -> vhs[b,h,l,d]
__global__ __launch_bounds__(256) void gemm_proj(
    const u16* __restrict__ Abf, const u16* __restrict__ BT,
    const float* __restrict__ rrb, const float* __restrict__ rwb,
    u16* __restrict__ out1, u16* __restrict__ out2, int mode)
{
    const int K = 1024;
    const int n0 = blockIdx.x * 64;
    const int m0 = blockIdx.y * 128;
    const int tid = threadIdx.x;
    const int w = tid >> 6, lane = tid & 63, g = lane >> 4, c = lane & 15;
    const int wr = m0 + w * 32;

    const f32x4 fzero = {0.f, 0.f, 0.f, 0.f};
    f32x4 acc[2][4];
    #pragma unroll
    for (int rt = 0; rt < 2; rt++) {
        #pragma unroll
        for (int ct = 0; ct < 4; ct++) acc[rt][ct] = fzero;
    }

    const u16* aptr0 = Abf + (size_t)(wr + c) * K + g * 8;
    const u16* aptr1 = Abf + (size_t)(wr + 16 + c) * K + g * 8;
    const u16* bptr0 = BT + (size_t)(n0 + c) * K + g * 8;
    const u16* bptr1 = BT + (size_t)(n0 + 16 + c) * K + g * 8;
    const u16* bptr2 = BT + (size_t)(n0 + 32 + c) * K + g * 8;
    const u16* bptr3 = BT + (size_t)(n0 + 48 + c) * K + g * 8;

    #pragma unroll 2
    for (int ks = 0; ks < 32; ks++) {
        const int off = ks * 32;
        bf16x8 a0 = *(const bf16x8*)(aptr0 + off);
        bf16x8 a1 = *(const bf16x8*)(aptr1 + off);
        bf16x8 b0 = *(const bf16x8*)(bptr0 + off);
        bf16x8 b1 = *(const bf16x8*)(bptr1 + off);
        bf16x8 b2 = *(const bf16x8*)(bptr2 + off);
        bf16x8 b3 = *(const bf16x8*)(bptr3 + off);
        acc[0][0] = mfma16(a0, b0, acc[0][0]);
        acc[1][0] = mfma16(a1, b0, acc[1][0]);
        acc[0][1] = mfma16(a0, b1, acc[0][1]);
        acc[1][1] = mfma16(a1, b1, acc[1][1]);
        acc[0][2] = mfma16(a0, b2, acc[0][2]);
        acc[1][2] = mfma16(a1, b2, acc[1][2]);
        acc[0][3] = mfma16(a0, b3, acc[0][3]);
        acc[1][3] = mfma16(a1, b3, acc[1][3]);
    }

    #pragma unroll
    for (int ct = 0; ct < 4; ct++) {
        const int n = n0 + ct * 16 + c;
        float b1v = 0.f, b2v = 0.f;
        if (mode == 0) { b1v = rrb[n]; b2v = rwb[n]; }
        #pragma unroll
        for (int rt = 0; rt < 2; rt++) {
            #pragma unroll
            for (int r = 0; r < 4; r++) {
                const int row = wr + rt * 16 + g * 4 + r;
                const int bb = row >> 10, l = row & 1023;
                const float v = acc[rt][ct][r];
                if (mode == 0) {
                    size_t idx = (((size_t)(bb * NH + (n >> 6))) * LEN + l) * HD + (n & 63);
                    out1[idx] = f2bf((v + b1v) * 0.125f);
                    out2[idx] = f2bf((v + b2v) * 0.125f);
                } else if (n < DM) {
                    size_t idx = (((size_t)(bb * NH + (n >> 6))) * LEN + l) * HD + (n & 63);
                    out1[idx] = f2bf(v);
                } else {
                    size_t idx = (((size_t)(bb * NH + ((n - DM) >> 6))) * LEN + l) * HD + (n & 63);
                    out2[idx] = f2bf(v);
                }
            }
        }
    }
}

// ---------------- vhs[b,h,l,d] -> vhsT[b,h,d,l] ----------------
__global__ void transpose_v(const u16* __restrict__ vhs, u16* __restrict__ vhsT) {
    __shared__ u16 tile[64][72];
    const int bhead = blockIdx.y;
    const int l0 = blockIdx.x * 64;
    const int tid = threadIdx.x;
    #pragma unroll
    for (int i = 0; i < 2; i++) {
        int idx = i * 256 + tid;
        int row = idx >> 3;
        int cg = (idx & 7) * 8;
        u16x8 v = *(const u16x8*)(vhs + ((size_t)bhead * LEN + l0 + row) * HD + cg);
        *(u16x8*)&tile[row][cg] = v;
    }
    __syncthreads();
    #pragma unroll
    for (int i = 0; i < 2; i++) {
        int idx = i * 256 + tid;
        int d = idx >> 3;
        int lg = (idx & 7) * 8;
        u16x8 o;
        #pragma unroll
        for (int j = 0; j < 8; j++) o[j] = tile[lg + j][d];
        *(u16x8*)(vhsT + ((size_t)bhead * HD + d) * LEN + l0 + lg) = o;
    }
}

// ---------------- fused rel-attention ----------------
// grid: (L/128, B*H). 4 waves/block, each wave owns 32 q-rows, flash loop over k.
__global__ __launch_bounds__(256) void attn_kernel(
    const u16* __restrict__ A1, const u16* __restrict__ A2,
    const u16* __restrict__ khs, const u16* __restrict__ vhsT,
    const u16* __restrict__ rbf, const int* __restrict__ mask,
    float* __restrict__ outp)
{
    __shared__ float Gl[4][32][68];   // band scores per wave
    __shared__ u16 Pl[4][32][40];     // P tile (bf16) per wave

    const int bh = blockIdx.y;
    const int b = bh >> 4, h = bh & 15;
    const int tid = threadIdx.x;
    const int w = tid >> 6, lane = tid & 63, g = lane >> 4, c = lane & 15;
    const int q0w = blockIdx.x * 128 + w * 32;

    const u16* A1p = A1 + ((size_t)bh * LEN + q0w) * HD;
    const u16* A2p = A2 + ((size_t)bh * LEN + q0w) * HD;
    const u16* Kp = khs + (size_t)bh * LEN * HD;
    const u16* Vp = vhsT + (size_t)bh * HD * LEN;
    const int* mp = mask + b * LEN;

    bf16x8 a1f[2][2], a2f[2][2];
    #pragma unroll
    for (int rt = 0; rt < 2; rt++) {
        #pragma unroll
        for (int kf = 0; kf < 2; kf++) {
            a1f[rt][kf] = *(const bf16x8*)(A1p + (rt * 16 + c) * HD + kf * 32 + g * 8);
            a2f[rt][kf] = *(const bf16x8*)(A2p + (rt * 16 + c) * HD + kf * 32 + g * 8);
        }
    }

    const f32x4 fzero = {0.f, 0.f, 0.f, 0.f};
    float mrow[2][4], lrow[2][4];
    f32x4 oacc[2][4];
    #pragma unroll
    for (int rt = 0; rt < 2; rt++) {
        #pragma unroll
        for (int r = 0; r < 4; r++) { mrow[rt][r] = -1e30f; lrow[rt][r] = 0.f; }
        #pragma unroll
        for (int dt = 0; dt < 4; dt++) oacc[rt][dt] = fzero;
    }

    for (int kt = 0; kt < 32; kt++) {
        const int c0 = kt * 32;
        f32x4 s[2][2];
        s[0][0] = fzero; s[0][1] = fzero; s[1][0] = fzero; s[1][1] = fzero;

        // ---- AC = A1 . K^T ----
        #pragma unroll
        for (int ct = 0; ct < 2; ct++) {
            #pragma unroll
            for (int kf = 0; kf < 2; kf++) {
                bf16x8 bk = *(const bf16x8*)(Kp + (size_t)(c0 + ct * 16 + c) * HD + kf * 32 + g * 8);
                s[0][ct] = mfma16(a1f[0][kf], bk, s[0][ct]);
                s[1][ct] = mfma16(a1f[1][kf], bk, s[1][ct]);
            }
        }

        // ---- band G[q, m] = A2[q] . r[base+m],  BD[q,k] = G[q, k+31-q] ----
        const int base = LEN + c0 - q0w - 31;
        #pragma unroll
        for (int gt = 0; gt < 4; gt++) {
            f32x4 g0 = fzero, g1 = fzero;
            #pragma unroll
            for (int kf = 0; kf < 2; kf++) {
                bf16x8 br = *(const bf16x8*)(rbf + (size_t)(base + gt * 16 + c) * HD + kf * 32 + g * 8);
                g0 = mfma16(a2f[0][kf], br, g0);
                g1 = mfma16(a2f[1][kf], br, g1);
            }
            #pragma unroll
            for (int r = 0; r < 4; r++) {
                Gl[w][g * 4 + r][gt * 16 + c] = g0[r];
                Gl[w][16 + g * 4 + r][gt * 16 + c] = g1[r];
            }
        }
        __syncthreads();

        // ---- gather BD + key mask ----
        const int mv0 = mp[c0 + c];
        const int mv1 = mp[c0 + 16 + c];
        #pragma unroll
        for (int rt = 0; rt < 2; rt++) {
            #pragma unroll
            for (int r = 0; r < 4; r++) {
                const int qw = rt * 16 + g * 4 + r;
                float s0 = s[rt][0][r] + Gl[w][qw][c + 31 - qw];
                float s1 = s[rt][1][r] + Gl[w][qw][16 + c + 31 - qw];
                s[rt][0][r] = mv0 ? s0 : -1e30f;
                s[rt][1][r] = mv1 ? s1 : -1e30f;
            }
        }

        // ---- online softmax ----
        #pragma unroll
        for (int rt = 0; rt < 2; rt++) {
            #pragma unroll
            for (int r = 0; r < 4; r++) {
                float t = fmaxf(s[rt][0][r], s[rt][1][r]);
                #pragma unroll
                for (int off = 1; off < 16; off <<= 1) t = fmaxf(t, __shfl_xor(t, off, 16));
                const float mold = mrow[rt][r];
                const float mnew = fmaxf(mold, t);
                const float alpha = __expf(mold - mnew);
                const float p0 = __expf(s[rt][0][r] - mnew);
                const float p1 = __expf(s[rt][1][r] - mnew);
                s[rt][0][r] = p0; s[rt][1][r] = p1;
                float rs = p0 + p1;
                #pragma unroll
                for (int off = 1; off < 16; off <<= 1) rs += __shfl_xor(rs, off, 16);
                lrow[rt][r] = lrow[rt][r] * alpha + rs;
                mrow[rt][r] = mnew;
                #pragma unroll
                for (int dt = 0; dt < 4; dt++) oacc[rt][dt][r] *= alpha;
            }
        }

        // ---- P -> LDS (bf16) ----
        #pragma unroll
        for (int rt = 0; rt < 2; rt++) {
            #pragma unroll
            for (int ct = 0; ct < 2; ct++) {
                #pragma unroll
                for (int r = 0; r < 4; r++)
                    Pl[w][rt * 16 + g * 4 + r][ct * 16 + c] = f2bf(s[rt][ct][r]);
            }
        }
        __syncthreads();

        // ---- PV ----
        bf16x8 pa0 = *(const bf16x8*)&Pl[w][c][g * 8];
        bf16x8 pa1 = *(const bf16x8*)&Pl[w][16 + c][g * 8];
        #pragma unroll
        for (int dt = 0; dt < 4; dt++) {
            bf16x8 bv = *(const bf16x8*)(Vp + (size_t)(dt * 16 + c) * LEN + c0 + g * 8);
            oacc[0][dt] = mfma16(pa0, bv, oacc[0][dt]);
            oacc[1][dt] = mfma16(pa1, bv, oacc[1][dt]);
        }
    }

    // ---- epilogue: normalize and store (fp32 out, [b, l, h*64+d]) ----
    #pragma unroll
    for (int rt = 0; rt < 2; rt++) {
        #pragma unroll
        for (int r = 0; r < 4; r++) {
            const float inv = lrow[rt][r] > 0.f ? 1.0f / lrow[rt][r] : 0.f;
            const int l = q0w + rt * 16 + g * 4 + r;
            #pragma unroll
            for (int dt = 0; dt < 4; dt++) {
                outp[((size_t)b * LEN + l) * DM + h * HD + dt * 16 + c] = oacc[rt][dt][r] * inv;
            }
        }
    }
}

extern "C" void kernel_launch(void* const* d_in, const int* in_sizes, int n_in,
                              void* d_out, int out_size, void* d_ws, size_t ws_size,
                              hipStream_t stream) {
    const float* q   = (const float*)d_in[0];
    const float* k   = (const float*)d_in[1];
    const int*   msk = (const int*)d_in[2];
    const float* pos = (const float*)d_in[3];
    const float* Wq  = (const float*)d_in[4];
    const float* Wkv = (const float*)d_in[5];
    const float* Wr  = (const float*)d_in[6];
    const float* rrb = (const float*)d_in[7];
    const float* rwb = (const float*)d_in[8];
    float* outp = (float*)d_out;
    char* ws = (char*)d_ws;

    u16* qbf  = (u16*)(ws + 0);              // 8 MB
    u16* kbf  = (u16*)(ws + 8388608);        // 8 MB
    u16* WqT  = (u16*)(ws + 16777216);       // 2 MB
    u16* WkvT = (u16*)(ws + 18874368);       // 4 MB
    u16* rbf  = (u16*)(ws + 23068672);       // 2064*64*2 (16 pad rows, never gathered)
    u16* A1   = (u16*)(ws + 23332864);       // 8 MB
    u16* A2   = (u16*)(ws + 31721472);       // 8 MB
    u16* khs  = (u16*)(ws + 40110080);       // 8 MB
    u16* vhs  = (u16*)(ws + 48498688);       // 8 MB
    u16* vhsT = (u16*)(ws + 56887296);       // 8 MB  (end: 65275904)

    cast_f32_bf16<<<4096, 256, 0, stream>>>(q, qbf, 1048576);
    cast_f32_bf16<<<4096, 256, 0, stream>>>(k, kbf, 1048576);
    transpose_cast<<<dim3(32, 32), dim3(32, 8), 0, stream>>>(Wq, WqT, 1024, 1024);
    transpose_cast<<<dim3(64, 32), dim3(32, 8), 0, stream>>>(Wkv, WkvT, 1024, 2048);
    r_proj<<<512, 256, 0, stream>>>(pos, Wr, rbf);
    gemm_proj<<<dim3(16, 32), 256, 0, stream>>>(qbf, WqT, rrb, rwb, A1, A2, 0);
    gemm_proj<<<dim3(32, 32), 256, 0, stream>>>(kbf, WkvT, nullptr, nullptr, khs, vhs, 1);
    transpose_v<<<dim3(16, 64), 256, 0, stream>>>(vhs, vhsT);
    attn_kernel<<<dim3(8, 64), 256, 0, stream>>>(A1, A2, khs, vhsT, rbf, msk, outp);
}